// Round 23
// baseline (67.482 us; speedup 1.0000x reference)
//
#include <hip/hip_runtime.h>
#include <math.h>

// HoltWintersDecomposition: x (8192, 2048) f32, sequential per-row recurrence.
// r23 = r19/r22 + bare-minimum producer (per-inst law: every producer inst
// costs ~4-5cy wall; chain-latency (r20) and barrier-drain (r22) changes were
// neutral, instruction-count changes convert at ~1.7-2x).
//   - Algebraic fold: D' = omg*oma*D + omg*ax + EPSg*ltn + gx
//       = fma(EPSg, ltn, fma(c2, D, W)),  c2 = (1-a)(1-g), W = c1*x,
//       c1 = a + g - a*g.  Removes pre/K from r19.
//   - x-preprocessing -> consumers: they compute (ax, W) = (a*x, c1*x) for the
//     NEXT tile into an interleaved AW LDS buffer (pairs; 132-float row stride,
//     528B = 16B-aligned, 4-bank lane spacing -> conflict-free b128).
//     Producer reads 1 ds_read_b128 per 2 steps and never touches x/global.
//   - Producer step: cl=fma(oma,lte,EPSa); cD=fma(c2,D,W); ltn=fma(ax,v,cl);
//     Dn=fma(EPSg,ltn,cD); un=rcp(Dn); vn=ltn*un  -> 5 VALU + 1 rcp + ~1 LDS.
//   - Consumers also: s = D*rcp(l), y = x*rcp(D) + stores (r17-r22 validated).
// Structure: 256 blocks x 32 rows; wave0 producer (lanes 0..31); waves 1-2
// consumers (preprocess next tile + store previous tile); lgkmcnt-only
// barriers (r22, safe: all cross-wave handoff is through LDS).
// Lessons: r6 parallel-in-time broken (s ~ 20*EPS); r4/r12/r17 never pack 2
// chains into one wave; r9 loads need >=1-tile lead (producer now has none).

constexpr int   T    = 2048;
constexpr int   B    = 8192;
constexpr int   RPB  = 32;        // rows per block
constexpr int   TT   = 64;        // steps per tile
constexpr int   NTI  = T / TT;    // 32 tiles
constexpr int   LSX  = 68;        // LT/DT stride words (272B rows, 16B-aligned)
constexpr int   AWS  = 132;       // AW stride words (528B rows, 16B-aligned)
constexpr float EPS  = 1e-8f;

// barrier that drains ONLY LDS counters; global loads/stores stay in flight
__device__ __forceinline__ void lds_barrier() {
    __builtin_amdgcn_sched_barrier(0);
    asm volatile("s_waitcnt lgkmcnt(0)" ::: "memory");
    __builtin_amdgcn_s_barrier();
    __builtin_amdgcn_sched_barrier(0);
}

__global__ __launch_bounds__(192, 1)
void hw_kernel(const float* __restrict__ x,
               const float* __restrict__ pla,
               const float* __restrict__ plg,
               float* __restrict__ out)
{
    __shared__ alignas(16) float LT[2][RPB][LSX];   // lte = l + EPS
    __shared__ alignas(16) float DT[2][RPB][LSX];   // D = lte * ste
    __shared__ alignas(16) float AW[2][RPB][AWS];   // (ax,W) interleaved pairs

    const int tid  = threadIdx.x;
    const int wid  = tid >> 6;        // 0 = producer, 1..2 = consumers
    const int lane = tid & 63;
    const int row0 = blockIdx.x * RPB;

    const float alpha = 1.0f / (1.0f + expf(-pla[0]));
    const float gamma = 1.0f / (1.0f + expf(-plg[0]));
    const float oma = 1.0f - alpha, omg = 1.0f - gamma;
    const float EPSa = EPS * alpha;
    const float EPSg = EPS * gamma;
    const float c1   = alpha + gamma - alpha * gamma;  // W = c1*x
    const float c2   = oma * omg;                      // D' = c2*D + W + EPSg*l'

    float* __restrict__ lout = out;
    float* __restrict__ sout = out + (size_t)B * T;
    float* __restrict__ yout = out + (size_t)2 * B * T;

    // store/preprocess lane mapping
    const int cr = lane >> 4;          // 0..3
    const int cc = (lane & 15) << 2;   // 0,4,...,60

    // consumer: l from LDS; s = D*rcp(l); y = x*rcp(D)
    auto store_tile = [&](int m, int itlo, int ithi) {
        const int bsel = m & 1;
        const int t0 = m * TT;
        #pragma unroll
        for (int it = itlo; it < ithi; ++it) {
            const int r = 4 * it + cr;
            const size_t g = (size_t)(row0 + r) * T + t0 + cc;
            const float4 vl = *reinterpret_cast<const float4*>(&LT[bsel][r][cc]);
            const float4 vd = *reinterpret_cast<const float4*>(&DT[bsel][r][cc]);
            const float4 xv = *reinterpret_cast<const float4*>(&x[g]);
            float4 vs, vy;
            vs.x = vd.x * __builtin_amdgcn_rcpf(vl.x);
            vs.y = vd.y * __builtin_amdgcn_rcpf(vl.y);
            vs.z = vd.z * __builtin_amdgcn_rcpf(vl.z);
            vs.w = vd.w * __builtin_amdgcn_rcpf(vl.w);
            vy.x = xv.x * __builtin_amdgcn_rcpf(vd.x);
            vy.y = xv.y * __builtin_amdgcn_rcpf(vd.y);
            vy.z = xv.z * __builtin_amdgcn_rcpf(vd.z);
            vy.w = xv.w * __builtin_amdgcn_rcpf(vd.w);
            *reinterpret_cast<float4*>(&lout[g]) = vl;
            *reinterpret_cast<float4*>(&sout[g]) = vs;
            *reinterpret_cast<float4*>(&yout[g]) = vy;
        }
    };

    // consumer: preprocess tile k -> AW[k&1]: pairs (ax, W) per step
    auto preprocess = [&](int k, int itlo, int ithi) {
        const int bsel = k & 1;
        const int t0 = k * TT;
        #pragma unroll
        for (int it = itlo; it < ithi; ++it) {
            const int r = 4 * it + cr;
            const size_t g = (size_t)(row0 + r) * T + t0 + cc;
            const float4 xv = *reinterpret_cast<const float4*>(&x[g]);
            float4 p0, p1;
            p0.x = alpha * xv.x; p0.y = c1 * xv.x;
            p0.z = alpha * xv.y; p0.w = c1 * xv.y;
            p1.x = alpha * xv.z; p1.y = c1 * xv.z;
            p1.z = alpha * xv.w; p1.w = c1 * xv.w;
            *reinterpret_cast<float4*>(&AW[bsel][r][2 * cc])     = p0;
            *reinterpret_cast<float4*>(&AW[bsel][r][2 * cc + 4]) = p1;
        }
    };

    if (wid == 0) {
        // ================= producer: LDS-only, 6 core insts/step ==========
        const bool act = lane < RPB;
        const float x0v = act ? x[(size_t)(row0 + lane) * T] : 1.0f;

        float lte = 0.0f;   // l + EPS
        float D   = 1.0f;   // lte * ste
        float v   = 1.0f;   // rcp(ste), carried as lte*rcp(D)

        auto do_step = [&](float ax, float W, float& lo, float& dsto) {
            const float cl  = __builtin_fmaf(oma, lte, EPSa);   // || with rcp
            const float cD  = __builtin_fmaf(c2, D, W);         // || with rcp
            const float ltn = __builtin_fmaf(ax, v, cl);        // chain
            const float Dn  = __builtin_fmaf(EPSg, ltn, cD);    // chain
            const float un  = __builtin_amdgcn_rcpf(Dn);        // chain (one rcp)
            const float vn  = ltn * un;                         // chain
            lo = ltn; dsto = Dn;
            lte = ltn; D = Dn; v = vn;
        };

        auto compute_tile = [&](int k, bool first) {
            const int bsel = k & 1;
            #pragma unroll
            for (int g = 0; g < 16; ++g) {
                const float4 r0 = *reinterpret_cast<const float4*>(&AW[bsel][lane][8 * g]);
                const float4 r1 = *reinterpret_cast<const float4*>(&AW[bsel][lane][8 * g + 4]);
                float4 lv, dv;
                if (first && g == 0) {
                    // t == 0: l0 = x0, s0 = 1 (primed): lte = x0+e, ste = 1+e
                    lte = x0v + EPS;
                    D   = lte * (1.0f + EPS);
                    v   = lte * __builtin_amdgcn_rcpf(D);
                    lv.x = lte; dv.x = D;
                    do_step(r0.z, r0.w, lv.y, dv.y);
                    do_step(r1.x, r1.y, lv.z, dv.z);
                    do_step(r1.z, r1.w, lv.w, dv.w);
                } else {
                    do_step(r0.x, r0.y, lv.x, dv.x);
                    do_step(r0.z, r0.w, lv.y, dv.y);
                    do_step(r1.x, r1.y, lv.z, dv.z);
                    do_step(r1.z, r1.w, lv.w, dv.w);
                }
                *reinterpret_cast<float4*>(&LT[bsel][lane][4 * g]) = lv;
                *reinterpret_cast<float4*>(&DT[bsel][lane][4 * g]) = dv;
            }
        };

        lds_barrier();                         // matches consumer preprocess(0)
        #pragma unroll 1
        for (int k = 0; k < NTI; ++k) {
            if (act) compute_tile(k, k == 0);
            lds_barrier();
        }
    } else {
        // ========== consumers: preprocess next + store previous ===========
        const int lo = (wid - 1) * 4;            // wave1: 0..3, wave2: 4..7
        preprocess(0, lo, lo + 4);
        lds_barrier();
        #pragma unroll 1
        for (int k = 0; k < NTI; ++k) {
            if (k + 1 < NTI) preprocess(k + 1, lo, lo + 4);
            if (k > 0)       store_tile(k - 1, lo, lo + 4);
            lds_barrier();
        }
    }

    // epilogue: tile 31 (buffer 1), all three waves split the 8 store groups
    {
        const int lo = (wid == 0) ? 0 : (wid == 1) ? 2 : 5;
        const int hi = (wid == 0) ? 2 : (wid == 1) ? 5 : 8;
        store_tile(NTI - 1, lo, hi);
    }
}

extern "C" void kernel_launch(void* const* d_in, const int* in_sizes, int n_in,
                              void* d_out, int out_size, void* d_ws, size_t ws_size,
                              hipStream_t stream) {
    const float* x   = (const float*)d_in[0];
    const float* pla = (const float*)d_in[1];
    const float* plg = (const float*)d_in[2];
    float* out = (float*)d_out;

    dim3 grid(B / RPB);    // 256 blocks -> one producer + 2 consumers per CU
    dim3 block(192);       // wave0 producer (32 rows), waves 1-2 consumers
    hw_kernel<<<grid, block, 0, stream>>>(x, pla, plg, out);
}

// Round 24
// 57.335 us; speedup vs baseline: 1.1770x; 1.1770x over previous
//
#include <hip/hip_runtime.h>
#include <math.h>

// HoltWintersDecomposition: x (8192, 2048) f32, sequential per-row recurrence.
// r24 = r19 (best register-fed producer) + state rescaling to 7 insts/step:
//   Per-inst law (r13..r23): producer wall ~ #insts x 4.5cy; latency moves
//   (r20/r22) are neutral; LDS feeds (r23) add latency the lone wave can't hide.
//   So cut COUNT with zero new memory ops: substitute L = lte/alpha, E = D/c1
//   (c1 = a+g-ag, c2 = (1-a)(1-g)) -> the recurrence uses RAW x (no ax/gx/W
//   premultiplies):
//     m  = x*L; cL = fma(oma,L,EPS); ie = fma(c2,E,x)   (|| with rcp)
//     u  = rcp(E); xlu = m*u; L' = fma(k3,xlu,cL); E' = fma(k2,L',ie)
//   k3 = a/c1, k2 = EPS*g*a/c1. Exactly r19/r23's validated algebra under
//   constant rescaling (r23's fold passed, absmax 16384).
//   Consumers reconstruct lte = a*L, D = c1*E (+2 muls/elem, big slack), then
//   the validated s = D*rcp(lte), y = x*rcp(D).
// Structure (r19): 256 blocks x 32 rows; wave0 producer (lanes 0..31, raw-x
// full-tile register prefetch, 1-tile lead); waves 1-2 consumers; lgkm-only
// barriers (r22-neutral, frees the store drain).
// Lessons: r6 parallel-in-time broken (s ~ 20*EPS); r9 loads need >=1-tile
// lead; r4/r12/r17 never pack 2 chains per wave; r23 never feed chain from LDS.

constexpr int   T    = 2048;
constexpr int   B    = 8192;
constexpr int   RPB  = 32;        // rows per block
constexpr int   TT   = 64;        // steps per tile
constexpr int   NTI  = T / TT;    // 32 tiles
constexpr int   LSX  = 68;        // LDS stride words: 272B rows, 16B-aligned
constexpr float EPS  = 1e-8f;

// barrier draining ONLY LDS counters; global loads/stores stay in flight
__device__ __forceinline__ void lds_barrier() {
    __builtin_amdgcn_sched_barrier(0);
    asm volatile("s_waitcnt lgkmcnt(0)" ::: "memory");
    __builtin_amdgcn_s_barrier();
    __builtin_amdgcn_sched_barrier(0);
}

__global__ __launch_bounds__(192, 1)
void hw_kernel(const float* __restrict__ x,
               const float* __restrict__ pla,
               const float* __restrict__ plg,
               float* __restrict__ out)
{
    __shared__ alignas(16) float LT[2][RPB][LSX];   // L = (l+EPS)/alpha
    __shared__ alignas(16) float ET[2][RPB][LSX];   // E = D/c1

    const int tid  = threadIdx.x;
    const int wid  = tid >> 6;        // 0 = producer, 1..2 = consumers
    const int lane = tid & 63;
    const int row0 = blockIdx.x * RPB;

    const float alpha = 1.0f / (1.0f + expf(-pla[0]));
    const float gamma = 1.0f / (1.0f + expf(-plg[0]));
    const float oma = 1.0f - alpha, omg = 1.0f - gamma;
    const float c1  = alpha + gamma - alpha * gamma;
    const float c2  = oma * omg;
    const float inv_a  = 1.0f / alpha;      // once, off-loop
    const float inv_c1 = 1.0f / c1;         // once, off-loop
    const float k3  = alpha * inv_c1;
    const float k2  = EPS * gamma * alpha * inv_c1;

    float* __restrict__ lout = out;
    float* __restrict__ sout = out + (size_t)B * T;
    float* __restrict__ yout = out + (size_t)2 * B * T;

    // store-phase lane mapping
    const int cr = lane >> 4;          // 0..3
    const int cc = (lane & 15) << 2;   // 0,4,...,60

    // consumer: reconstruct lte = a*L, D = c1*E; s = D*rcp(lte); y = x*rcp(D)
    auto store_tile = [&](int m, int itlo, int ithi) {
        const int bsel = m & 1;
        const int t0 = m * TT;
        #pragma unroll
        for (int it = itlo; it < ithi; ++it) {
            const int r = 4 * it + cr;
            const size_t g = (size_t)(row0 + r) * T + t0 + cc;
            const float4 vL = *reinterpret_cast<const float4*>(&LT[bsel][r][cc]);
            const float4 vE = *reinterpret_cast<const float4*>(&ET[bsel][r][cc]);
            const float4 xv = *reinterpret_cast<const float4*>(&x[g]);
            float4 vl, vd, vs, vy;
            vl.x = alpha * vL.x;  vl.y = alpha * vL.y;
            vl.z = alpha * vL.z;  vl.w = alpha * vL.w;
            vd.x = c1 * vE.x;     vd.y = c1 * vE.y;
            vd.z = c1 * vE.z;     vd.w = c1 * vE.w;
            vs.x = vd.x * __builtin_amdgcn_rcpf(vl.x);
            vs.y = vd.y * __builtin_amdgcn_rcpf(vl.y);
            vs.z = vd.z * __builtin_amdgcn_rcpf(vl.z);
            vs.w = vd.w * __builtin_amdgcn_rcpf(vl.w);
            vy.x = xv.x * __builtin_amdgcn_rcpf(vd.x);
            vy.y = xv.y * __builtin_amdgcn_rcpf(vd.y);
            vy.z = xv.z * __builtin_amdgcn_rcpf(vd.z);
            vy.w = xv.w * __builtin_amdgcn_rcpf(vd.w);
            *reinterpret_cast<float4*>(&lout[g]) = vl;
            *reinterpret_cast<float4*>(&sout[g]) = vs;
            *reinterpret_cast<float4*>(&yout[g]) = vy;
        }
    };

    if (wid == 0) {
        // ================= producer: 7 insts/step, raw x from registers ====
        const bool act = lane < RPB;
        const float* __restrict__ xrow = x + (size_t)(row0 + (act ? lane : 0)) * T;

        float L = 0.0f;     // (l + EPS) / alpha
        float E = 1.0f;     // D / c1
        float4 XA[16], XB[16];

        auto loadX = [&](float4* Xb, int k) {
            const float* p = xrow + k * TT;
            #pragma unroll
            for (int i = 0; i < 16; ++i)
                Xb[i] = *reinterpret_cast<const float4*>(p + 4 * i);
        };

        auto do_step = [&](float xt, float& Lo, float& Eo) {
            const float m   = xt * L;                        // || with rcp
            const float cL  = __builtin_fmaf(oma, L, EPS);   // || with rcp
            const float ie  = __builtin_fmaf(c2, E, xt);     // || with rcp
            const float u   = __builtin_amdgcn_rcpf(E);      // chain (one rcp)
            const float xlu = m * u;                         // chain
            const float Ln  = __builtin_fmaf(k3, xlu, cL);   // chain
            const float En  = __builtin_fmaf(k2, Ln, ie);    // chain
            Lo = Ln; Eo = En;
            L = Ln; E = En;
        };

        auto compute_tile = [&](const float4* Xb, int k, bool first) {
            const int bsel = k & 1;
            #pragma unroll
            for (int g = 0; g < 16; ++g) {
                const float4 xv = Xb[g];
                float4 Lv, Ev;
                if (first && g == 0) {
                    // t == 0: lte = x0+EPS, ste = 1+EPS (primed, validated)
                    const float lte0 = xv.x + EPS;
                    L = lte0 * inv_a;
                    E = (lte0 * (1.0f + EPS)) * inv_c1;
                    Lv.x = L; Ev.x = E;
                    do_step(xv.y, Lv.y, Ev.y);
                    do_step(xv.z, Lv.z, Ev.z);
                    do_step(xv.w, Lv.w, Ev.w);
                } else {
                    do_step(xv.x, Lv.x, Ev.x);
                    do_step(xv.y, Lv.y, Ev.y);
                    do_step(xv.z, Lv.z, Ev.z);
                    do_step(xv.w, Lv.w, Ev.w);
                }
                *reinterpret_cast<float4*>(&LT[bsel][lane][4 * g]) = Lv;
                *reinterpret_cast<float4*>(&ET[bsel][lane][4 * g]) = Ev;
            }
        };

        if (act) { loadX(XA, 0); loadX(XB, 1); }
        if (act) compute_tile(XA, 0, true);     // one-time vmcnt wait on XA
        lds_barrier();

        #pragma unroll 1
        for (int k = 1; k < NTI - 1; k += 2) {
            if (act) { loadX(XA, k + 1); compute_tile(XB, k, false); }
            lds_barrier();
            if (act) { loadX(XB, k + 2); compute_tile(XA, k + 1, false); }
            lds_barrier();
        }
        if (act) compute_tile(XB, NTI - 1, false);
        lds_barrier();
    } else {
        // ================= consumers: stores + reconstruction =============
        const int lo = (wid - 1) * 4;            // wave1: 0..3, wave2: 4..7
        #pragma unroll 1
        for (int k = 0; k < NTI; ++k) {
            if (k > 0) store_tile(k - 1, lo, lo + 4);
            lds_barrier();
        }
    }

    // epilogue: tile 31 (buffer 1), all three waves split the 8 store groups
    {
        const int lo = (wid == 0) ? 0 : (wid == 1) ? 2 : 5;
        const int hi = (wid == 0) ? 2 : (wid == 1) ? 5 : 8;
        store_tile(NTI - 1, lo, hi);
    }
}

extern "C" void kernel_launch(void* const* d_in, const int* in_sizes, int n_in,
                              void* d_out, int out_size, void* d_ws, size_t ws_size,
                              hipStream_t stream) {
    const float* x   = (const float*)d_in[0];
    const float* pla = (const float*)d_in[1];
    const float* plg = (const float*)d_in[2];
    float* out = (float*)d_out;

    dim3 grid(B / RPB);    // 256 blocks -> one producer + 2 consumers per CU
    dim3 block(192);       // wave0 producer (32 rows), waves 1-2 consumers
    hw_kernel<<<grid, block, 0, stream>>>(x, pla, plg, out);
}